// Round 3
// baseline (13454.800 us; speedup 1.0000x reference)
//
#include <hip/hip_runtime.h>

// x[2048,64,2] -> MLP(2->16 relu ->16) -> 8x LSTM(H=64) -> MLP(64->32 relu ->4)
// fp32 in/out. LSTM via split-bf16 MFMA (3-term, ~fp32 accuracy).
//
// Round 3: layer-pipelined persistent LSTM. Grid 1024 = 8 layers x 128 mgroups,
// M=16 batch rows/block (full MFMA row utilization), 4 blocks/CU resident.
// Layer l step t waits on layer l-1 step t via agent-scope release/acquire
// progress counters; h flows through global ring buffers (depth = full T if
// ws_size allows, else 8 with producer backpressure).

#define BATCH 2048
#define TT 64
#define HH 64

typedef short bf16x8 __attribute__((ext_vector_type(8)));
typedef float f32x4 __attribute__((ext_vector_type(4)));

#define LDPS 136   // panel row stride in shorts (16B-aligned rows, 2-way-free banks)
#define GS   260   // g_s row stride in floats (breaks 4-way write conflicts)

__device__ __forceinline__ float sigmoid_fast(float x) {
    x = fminf(15.f, fmaxf(-15.f, x));
    return __builtin_amdgcn_rcpf(1.f + __expf(-x));
}
__device__ __forceinline__ float tanh_fast(float x) {
    x = fminf(15.f, fmaxf(-15.f, x));
    const float e = __expf(-2.f * x);
    return (1.f - e) * __builtin_amdgcn_rcpf(1.f + e);
}
__device__ __forceinline__ void split2(float x, unsigned short& hi, unsigned short& lo) {
    const unsigned u = __float_as_uint(x);
    hi = (unsigned short)(u >> 16);
    const float r = x - __uint_as_float(u & 0xFFFF0000u);  // exact
    lo = (unsigned short)(__float_as_uint(r) >> 16);
}

__device__ __forceinline__ int ld_acq(const int* p) {
    return __hip_atomic_load(p, __ATOMIC_ACQUIRE, __HIP_MEMORY_SCOPE_AGENT);
}
__device__ __forceinline__ void st_rel(int* p, int v) {
    __hip_atomic_store(p, v, __ATOMIC_RELEASE, __HIP_MEMORY_SCOPE_AGENT);
}

// ---------------- input MLP: 2 -> 16 relu -> 16 ----------------
__global__ __launch_bounds__(256)
void mlp_in_kernel(const float* __restrict__ x,
                   const float* __restrict__ w1, const float* __restrict__ b1,
                   const float* __restrict__ w2, const float* __restrict__ b2,
                   float* __restrict__ out) {
    const int gid = blockIdx.x * 256 + threadIdx.x;
    const float x0 = x[gid * 2 + 0];
    const float x1 = x[gid * 2 + 1];
    float hid[16];
#pragma unroll
    for (int j = 0; j < 16; ++j) {
        float v = fmaf(x1, w1[j * 2 + 1], fmaf(x0, w1[j * 2 + 0], b1[j]));
        hid[j] = fmaxf(0.f, v);
    }
    float o[16];
#pragma unroll
    for (int oo = 0; oo < 16; ++oo) {
        float acc = b2[oo];
#pragma unroll
        for (int j = 0; j < 16; ++j) acc = fmaf(hid[j], w2[oo * 16 + j], acc);
        o[oo] = acc;
    }
    float4* op = (float4*)(out + gid * 16);
#pragma unroll
    for (int q = 0; q < 4; ++q) {
        float4 v;
        v.x = o[q * 4 + 0]; v.y = o[q * 4 + 1]; v.z = o[q * 4 + 2]; v.w = o[q * 4 + 3];
        op[q] = v;
    }
}

__global__ void clear_flags_kernel(int* flags, int n) {
    for (int i = threadIdx.x; i < n; i += 256) flags[i] = 0;
}

// ---------------- one pipelined LSTM layer body ----------------
// I = real input width; IPAD = padded x-region; K = IPAD + 64.
template <int I, int IPAD>
__device__ __forceinline__ void run_layer(
    const float* __restrict__ inp, int inD,
    float* __restrict__ outp, int outD,
    const float* __restrict__ w_ih, const float* __restrict__ w_hh,
    const float* __restrict__ b_ih, const float* __restrict__ b_hh,
    int base, unsigned short* ph, unsigned short* pl, float* gs,
    const int* prod_prev, int* cons_prev, const int* cons_own, int* prod_own, int D) {
    constexpr int K = IPAD + 64;
    constexpr int KT = K / 32;

    const int tid = threadIdx.x;
    const int wave = tid >> 6;
    const int lane = tid & 63;
    const int l16 = lane & 15;
    const int quad = lane >> 4;

    // zero panels (pad + initial h=0)
    for (int e = tid; e < 16 * LDPS; e += 256) { ph[e] = 0; pl[e] = 0; }

    // --- weight B-fragments (split hi/lo) in registers ---
    bf16x8 bhi[KT][4], blo[KT][4];
    float bias[4];
#pragma unroll
    for (int nt = 0; nt < 4; ++nt) {
        const int n = wave * 64 + nt * 16 + l16;
        bias[nt] = b_ih[n] + b_hh[n];
#pragma unroll
        for (int kt = 0; kt < KT; ++kt) {
#pragma unroll
            for (int j = 0; j < 8; ++j) {
                const int k = kt * 32 + quad * 8 + j;
                float w = 0.f;
                if (k < I) w = w_ih[n * I + k];
                else if (k >= IPAD) w = w_hh[n * 64 + (k - IPAD)];
                unsigned short h_, l_;
                split2(w, h_, l_);
                bhi[kt][nt][j] = (short)h_;
                blo[kt][nt][j] = (short)l_;
            }
        }
    }

    float c[4] = {0.f, 0.f, 0.f, 0.f};   // cell state: slot r -> (m = r*4 + wave, j = lane)

    for (int t = 0; t < TT; ++t) {
        // ---- sync: wait for producer step t; backpressure on own ring ----
        if (tid == 0) {
            if (prod_prev) { while (ld_acq(prod_prev) < t + 1) __builtin_amdgcn_s_sleep(1); }
            if (cons_own)  { const int need = t - D + 1;
                             while (ld_acq(cons_own) < need) __builtin_amdgcn_s_sleep(1); }
        }
        __syncthreads();  // sb1

        // ---- phase A: stage input step t into panel (split bf16) ----
        if (I == 64) {
#pragma unroll
            for (int r = 0; r < 4; ++r) {
                const int m = r * 4 + (tid >> 6);
                const int k = tid & 63;
                const float v = inp[((size_t)(base + m) * inD + (t & (inD - 1))) * 64 + k];
                unsigned short h_, l_;
                split2(v, h_, l_);
                ph[m * LDPS + k] = h_;
                pl[m * LDPS + k] = l_;
            }
        } else {
            const int m = tid >> 4, k = tid & 15;
            const float v = inp[((size_t)(base + m) * inD + (t & (inD - 1))) * 16 + k];
            unsigned short h_, l_;
            split2(v, h_, l_);
            ph[m * LDPS + k] = h_;
            pl[m * LDPS + k] = l_;
        }
        __syncthreads();  // sb2
        if (tid == 0 && cons_prev) st_rel(cons_prev, t + 1);  // freed ring slot t of layer l-1

        // ---- phase B: gates = bias + in @ W^T (3-term split-bf16 MFMA) ----
        f32x4 acc[4];
#pragma unroll
        for (int nt = 0; nt < 4; ++nt) {
            acc[nt][0] = bias[nt]; acc[nt][1] = bias[nt];
            acc[nt][2] = bias[nt]; acc[nt][3] = bias[nt];
        }
#pragma unroll
        for (int kt = 0; kt < KT; ++kt) {
            const int aoff = l16 * LDPS + kt * 32 + quad * 8;
            const bf16x8 ahi = *(const bf16x8*)&ph[aoff];
            const bf16x8 alo = *(const bf16x8*)&pl[aoff];
#pragma unroll
            for (int nt = 0; nt < 4; ++nt) {
                acc[nt] = __builtin_amdgcn_mfma_f32_16x16x32_bf16(ahi, bhi[kt][nt], acc[nt], 0, 0, 0);
                acc[nt] = __builtin_amdgcn_mfma_f32_16x16x32_bf16(alo, bhi[kt][nt], acc[nt], 0, 0, 0);
                acc[nt] = __builtin_amdgcn_mfma_f32_16x16x32_bf16(ahi, blo[kt][nt], acc[nt], 0, 0, 0);
            }
        }
        // D layout: row = quad*4 + r, col = l16; all 16 rows real now.
#pragma unroll
        for (int nt = 0; nt < 4; ++nt) {
            const int col = wave * 64 + nt * 16 + l16;
#pragma unroll
            for (int r = 0; r < 4; ++r) gs[(quad * 4 + r) * GS + col] = acc[nt][r];
        }
        __syncthreads();  // sb3

        // ---- phase C: elementwise update, 4 (m,j) slots per thread ----
        const int j = tid & 63;
#pragma unroll
        for (int r = 0; r < 4; ++r) {
            const int m = r * 4 + (tid >> 6);
            const float gi = gs[m * GS + 0 + j];
            const float gf = gs[m * GS + 64 + j];
            const float gg = gs[m * GS + 128 + j];
            const float go = gs[m * GS + 192 + j];
            const float iv = sigmoid_fast(gi), fv = sigmoid_fast(gf);
            const float gv = tanh_fast(gg), ov = sigmoid_fast(go);
            c[r] = fv * c[r] + iv * gv;
            const float h = ov * tanh_fast(c[r]);
            unsigned short h_, l_;
            split2(h, h_, l_);
            ph[m * LDPS + IPAD + j] = h_;
            pl[m * LDPS + IPAD + j] = l_;
            outp[((size_t)(base + m) * outD + (t & (outD - 1))) * 64 + j] = h;
        }
        __threadfence();
        __syncthreads();  // sb4
        if (tid == 0 && prod_own) st_rel(prod_own, t + 1);
    }
}

// ---------------- pipelined 8-layer LSTM kernel ----------------
__global__ __launch_bounds__(256, 4)
void lstm_pipe(const float* __restrict__ buf_mlp,
               const float* __restrict__ w_ih0, const float* __restrict__ w_hh0,
               const float* __restrict__ b_ih0, const float* __restrict__ b_hh0,
               const float* __restrict__ w_ih, const float* __restrict__ w_hh,
               const float* __restrict__ b_ih, const float* __restrict__ b_hh,
               float* __restrict__ rings, float* __restrict__ finalb,
               int* __restrict__ prod, int* __restrict__ cons, int D) {
    __shared__ unsigned short ph[16 * LDPS];
    __shared__ unsigned short pl[16 * LDPS];
    __shared__ float gs[16 * GS];

    const int l = blockIdx.x >> 7;    // layer 0..7 (low indices dispatch first)
    const int g = blockIdx.x & 127;   // mgroup: bx%8 == g%8 -> same XCD across layers
    const int base = g * 16;
    const size_t ringsz = (size_t)BATCH * D * 64;

    if (l == 0) {
        run_layer<16, 32>(buf_mlp, 64, rings, D,
                          w_ih0, w_hh0, b_ih0, b_hh0, base, ph, pl, gs,
                          nullptr, nullptr, &cons[g], &prod[g], D);
    } else {
        const float* in = rings + (size_t)(l - 1) * ringsz;
        float* out = (l == 7) ? finalb : rings + (size_t)l * ringsz;
        run_layer<64, 64>(in, D, out, (l == 7) ? 64 : D,
                          w_ih + (size_t)(l - 1) * 256 * 64, w_hh + (size_t)(l - 1) * 256 * 64,
                          b_ih + (size_t)(l - 1) * 256, b_hh + (size_t)(l - 1) * 256,
                          base, ph, pl, gs,
                          &prod[(l - 1) * 128 + g], &cons[(l - 1) * 128 + g],
                          (l < 7) ? &cons[l * 128 + g] : nullptr,
                          (l < 7) ? &prod[l * 128 + g] : nullptr, D);
    }
}

// ---------------- output MLP: 64 -> 32 relu -> 4 ----------------
__global__ __launch_bounds__(256)
void mlp_out_kernel(const float* __restrict__ hin,
                    const float* __restrict__ wo1, const float* __restrict__ bo1,
                    const float* __restrict__ wo2, const float* __restrict__ bo2,
                    float* __restrict__ out) {
    __shared__ __align__(16) float wo1_s[32 * 64];
    __shared__ float bo1_s[32];
    __shared__ float wo2_s[4 * 32];
    __shared__ float bo2_s[4];
    const int tid = threadIdx.x;
    for (int e = tid; e < 32 * 64; e += 256) wo1_s[e] = wo1[e];
    if (tid < 32) bo1_s[tid] = bo1[tid];
    if (tid < 128) wo2_s[tid] = wo2[tid];
    if (tid < 4) bo2_s[tid] = bo2[tid];
    __syncthreads();

    const int gid = blockIdx.x * 256 + tid;
    const float4* hv = (const float4*)(hin + gid * 64);
    float4 h[16];
#pragma unroll
    for (int q = 0; q < 16; ++q) h[q] = hv[q];

    float m1[32];
#pragma unroll
    for (int o = 0; o < 32; ++o) {
        float acc = bo1_s[o];
        const float4* wrow = (const float4*)(wo1_s + o * 64);
#pragma unroll
        for (int q = 0; q < 16; ++q) {
            const float4 w = wrow[q];
            acc = fmaf(h[q].x, w.x, acc);
            acc = fmaf(h[q].y, w.y, acc);
            acc = fmaf(h[q].z, w.z, acc);
            acc = fmaf(h[q].w, w.w, acc);
        }
        m1[o] = fmaxf(0.f, acc);
    }
    float r[4];
#pragma unroll
    for (int q = 0; q < 4; ++q) {
        float acc = bo2_s[q];
#pragma unroll
        for (int o = 0; o < 32; ++o) acc = fmaf(m1[o], wo2_s[q * 32 + o], acc);
        r[q] = acc;
    }
    float4 res;
    res.x = r[0]; res.y = r[1]; res.z = r[2]; res.w = r[3];
    ((float4*)out)[gid] = res;
}

extern "C" void kernel_launch(void* const* d_in, const int* in_sizes, int n_in,
                              void* d_out, int out_size, void* d_ws, size_t ws_size,
                              hipStream_t stream) {
    const float* x     = (const float*)d_in[0];
    const float* w1    = (const float*)d_in[1];
    const float* b1    = (const float*)d_in[2];
    const float* w2    = (const float*)d_in[3];
    const float* b2    = (const float*)d_in[4];
    const float* w_ih0 = (const float*)d_in[5];
    const float* w_hh0 = (const float*)d_in[6];
    const float* b_ih0 = (const float*)d_in[7];
    const float* b_hh0 = (const float*)d_in[8];
    const float* w_ih  = (const float*)d_in[9];
    const float* w_hh  = (const float*)d_in[10];
    const float* b_ih  = (const float*)d_in[11];
    const float* b_hh  = (const float*)d_in[12];
    const float* wo1   = (const float*)d_in[13];
    const float* bo1   = (const float*)d_in[14];
    const float* wo2   = (const float*)d_in[15];
    const float* bo2   = (const float*)d_in[16];

    float* ws = (float*)d_ws;
    const size_t ws_floats = ws_size / 4;

    // layout: buf_mlp | 7 rings (depth D) | final [B,T,64] | flags (2x7x128 ints)
    const size_t mlp_f   = (size_t)BATCH * TT * 16;          // 2.10M floats
    const size_t final_f = (size_t)BATCH * TT * 64;          // 8.39M floats
    const size_t need_full = mlp_f + 7 * final_f + final_f + 2048;
    const int D = (ws_floats >= need_full) ? 64 : 8;         // full rings if ws allows

    float* buf_mlp = ws;
    float* rings   = buf_mlp + mlp_f;
    float* finalb  = rings + (size_t)7 * BATCH * D * 64;
    int*   flags   = (int*)(finalb + final_f);
    int*   prod    = flags;          // 7*128
    int*   cons    = flags + 7 * 128;

    const int nbt_blocks = (BATCH * TT) / 256;  // 512

    clear_flags_kernel<<<1, 256, 0, stream>>>(flags, 2 * 7 * 128);
    mlp_in_kernel<<<nbt_blocks, 256, 0, stream>>>(x, w1, b1, w2, b2, buf_mlp);
    lstm_pipe<<<1024, 256, 0, stream>>>(buf_mlp, w_ih0, w_hh0, b_ih0, b_hh0,
                                        w_ih, w_hh, b_ih, b_hh,
                                        rings, finalb, prod, cons, D);
    mlp_out_kernel<<<nbt_blocks, 256, 0, stream>>>(finalb, wo1, bo1, wo2, bo2, (float*)d_out);
}

// Round 4
// 644.778 us; speedup vs baseline: 20.8673x; 20.8673x over previous
//
#include <hip/hip_runtime.h>

// x[2048,64,2] -> MLP(2->16 relu ->16) -> 8x LSTM(H=64) -> MLP(64->32 relu ->4)
// fp32 in/out. LSTM via split-bf16 MFMA (3-term, ~fp32 accuracy).
//
// Round 4: sequential per-layer launches (round-3 pipeline spilled & deadlock-prone).
// Per layer: grid 128 x 256 threads, M=16 batch rows/block (full A-tile).
//   - wave w computes gates i,f,g,o for j in [16w,16w+16): phase C is register-local
//   - parity double-buffered LDS panel (bf16 hi/lo planes) -> 1 barrier/step
//   - x_{t+1} register-prefetched during step t
//   - __launch_bounds__(256,1): 512-VGPR budget, weights (~128 VGPRs) stay resident

#define BATCH 2048
#define TT 64
#define HH 64

typedef short bf16x8 __attribute__((ext_vector_type(8)));
typedef float f32x4 __attribute__((ext_vector_type(4)));

__device__ __forceinline__ float sigmoid_fast(float x) {
    x = fminf(15.f, fmaxf(-15.f, x));
    return __builtin_amdgcn_rcpf(1.f + __expf(-x));
}
__device__ __forceinline__ float tanh_fast(float x) {
    x = fminf(15.f, fmaxf(-15.f, x));
    const float e = __expf(-2.f * x);
    return (1.f - e) * __builtin_amdgcn_rcpf(1.f + e);
}
__device__ __forceinline__ void split2(float x, unsigned short& hi, unsigned short& lo) {
    const unsigned u = __float_as_uint(x);
    hi = (unsigned short)(u >> 16);
    const float r = x - __uint_as_float(u & 0xFFFF0000u);  // exact
    lo = (unsigned short)(__float_as_uint(r) >> 16);
}

// ---------------- input MLP: 2 -> 16 relu -> 16 ----------------
__global__ __launch_bounds__(256)
void mlp_in_kernel(const float* __restrict__ x,
                   const float* __restrict__ w1, const float* __restrict__ b1,
                   const float* __restrict__ w2, const float* __restrict__ b2,
                   float* __restrict__ out) {
    const int gid = blockIdx.x * 256 + threadIdx.x;
    const float x0 = x[gid * 2 + 0];
    const float x1 = x[gid * 2 + 1];
    float hid[16];
#pragma unroll
    for (int j = 0; j < 16; ++j) {
        float v = fmaf(x1, w1[j * 2 + 1], fmaf(x0, w1[j * 2 + 0], b1[j]));
        hid[j] = fmaxf(0.f, v);
    }
    float o[16];
#pragma unroll
    for (int oo = 0; oo < 16; ++oo) {
        float acc = b2[oo];
#pragma unroll
        for (int j = 0; j < 16; ++j) acc = fmaf(hid[j], w2[oo * 16 + j], acc);
        o[oo] = acc;
    }
    float4* op = (float4*)(out + gid * 16);
#pragma unroll
    for (int q = 0; q < 4; ++q) {
        float4 v;
        v.x = o[q * 4 + 0]; v.y = o[q * 4 + 1]; v.z = o[q * 4 + 2]; v.w = o[q * 4 + 3];
        op[q] = v;
    }
}

// ---------------- LSTM layer, split-bf16 MFMA, M=16 ----------------
// I = real input width; IPAD = padded x-region; K = IPAD + 64.
template <int I, int IPAD>
__global__ __launch_bounds__(256, 1)
void lstm_layer(const float* __restrict__ xin,
                const float* __restrict__ w_ih, const float* __restrict__ w_hh,
                const float* __restrict__ b_ih, const float* __restrict__ b_hh,
                float* __restrict__ hout) {
    constexpr int K = IPAD + 64;
    constexpr int KT = K / 32;
    constexpr int LDP = K + 16;                 // panel row stride in shorts
    __shared__ unsigned short ph[2][16 * LDP];  // parity panels, hi plane
    __shared__ unsigned short pl[2][16 * LDP];  // lo plane

    const int tid = threadIdx.x;
    const int wave = tid >> 6, lane = tid & 63, l16 = lane & 15, quad = lane >> 4;
    const int base = blockIdx.x * 16;

    for (int e = tid; e < 16 * LDP; e += 256) {
        ph[0][e] = 0; pl[0][e] = 0; ph[1][e] = 0; pl[1][e] = 0;
    }

    // --- weight B-fragments: wave w owns gates i,f,g,o for j in [16w,16w+16) ---
    // frag[kt][g]: lane(quad,l16) holds B[k=kt*32+quad*8+j][n=g*64+wave*16+l16]
    bf16x8 bhi[KT][4], blo[KT][4];
    float bias[4];
#pragma unroll
    for (int g = 0; g < 4; ++g) {
        const int n = g * 64 + wave * 16 + l16;
        bias[g] = b_ih[n] + b_hh[n];
#pragma unroll
        for (int kt = 0; kt < KT; ++kt) {
#pragma unroll
            for (int j = 0; j < 8; ++j) {
                const int k = kt * 32 + quad * 8 + j;
                float w = 0.f;
                if (k < I) w = w_ih[n * I + k];
                else if (k >= IPAD) w = w_hh[n * 64 + (k - IPAD)];
                unsigned short h_, l_;
                split2(w, h_, l_);
                bhi[kt][g][j] = (short)h_;
                blo[kt][g][j] = (short)l_;
            }
        }
    }

    float c[4] = {0.f, 0.f, 0.f, 0.f};  // cell: slot r -> (m = quad*4 + r, j = wave*16+l16)
    const int cj = wave * 16 + l16;

    // --- staging helpers: thread -> (row am, col-group ak) ---
    const int am = tid >> 4;
    const int ak = tid & 15;

    float4 xr4;
    float xr1;
    if (I == 64) xr4 = *(const float4*)&xin[((size_t)(base + am) * TT + 0) * 64 + ak * 4];
    else         xr1 = xin[((size_t)(base + am) * TT + 0) * 16 + ak];

    // phase A(0) into panel 0
    if (I == 64) {
        unsigned short h0, h1, h2, h3, l0, l1, l2, l3;
        split2(xr4.x, h0, l0); split2(xr4.y, h1, l1);
        split2(xr4.z, h2, l2); split2(xr4.w, h3, l3);
        uint2 hv, lv;
        hv.x = (unsigned)h0 | ((unsigned)h1 << 16); hv.y = (unsigned)h2 | ((unsigned)h3 << 16);
        lv.x = (unsigned)l0 | ((unsigned)l1 << 16); lv.y = (unsigned)l2 | ((unsigned)l3 << 16);
        *(uint2*)&ph[0][am * LDP + ak * 4] = hv;
        *(uint2*)&pl[0][am * LDP + ak * 4] = lv;
    } else {
        unsigned short h_, l_;
        split2(xr1, h_, l_);
        ph[0][am * LDP + ak] = h_;
        pl[0][am * LDP + ak] = l_;
    }
    // prefetch x(1)
    if (I == 64) xr4 = *(const float4*)&xin[((size_t)(base + am) * TT + 1) * 64 + ak * 4];
    else         xr1 = xin[((size_t)(base + am) * TT + 1) * 16 + ak];
    __syncthreads();

    for (int t = 0; t < TT; ++t) {
        const int pb = t & 1;
        const unsigned short* php = ph[pb];
        const unsigned short* plp = pl[pb];
        unsigned short* phn = ph[pb ^ 1];
        unsigned short* pln = pl[pb ^ 1];

        // ---- phase B: gates = bias + [x|h] @ W^T (3-term split-bf16 MFMA) ----
        f32x4 acc[4];
#pragma unroll
        for (int g = 0; g < 4; ++g) {
            acc[g][0] = bias[g]; acc[g][1] = bias[g];
            acc[g][2] = bias[g]; acc[g][3] = bias[g];
        }
#pragma unroll
        for (int kt = 0; kt < KT; ++kt) {
            const int aoff = l16 * LDP + kt * 32 + quad * 8;
            const bf16x8 ahi = *(const bf16x8*)&php[aoff];
            const bf16x8 alo = *(const bf16x8*)&plp[aoff];
#pragma unroll
            for (int g = 0; g < 4; ++g) {
                acc[g] = __builtin_amdgcn_mfma_f32_16x16x32_bf16(ahi, bhi[kt][g], acc[g], 0, 0, 0);
                acc[g] = __builtin_amdgcn_mfma_f32_16x16x32_bf16(alo, bhi[kt][g], acc[g], 0, 0, 0);
                acc[g] = __builtin_amdgcn_mfma_f32_16x16x32_bf16(ahi, blo[kt][g], acc[g], 0, 0, 0);
            }
        }

        // ---- phase C: register-local LSTM update (D row = quad*4+r, col = l16) ----
#pragma unroll
        for (int r = 0; r < 4; ++r) {
            const int m = quad * 4 + r;
            const float iv = sigmoid_fast(acc[0][r]);
            const float fv = sigmoid_fast(acc[1][r]);
            const float gv = tanh_fast(acc[2][r]);
            const float ov = sigmoid_fast(acc[3][r]);
            c[r] = fv * c[r] + iv * gv;
            const float h = ov * tanh_fast(c[r]);
            unsigned short h_, l_;
            split2(h, h_, l_);
            phn[m * LDP + IPAD + cj] = h_;
            pln[m * LDP + IPAD + cj] = l_;
            hout[((size_t)(base + m) * TT + t) * HH + cj] = h;
        }

        // ---- phase A(t+1): stage prefetched x into next panel ----
        if (I == 64) {
            unsigned short h0, h1, h2, h3, l0, l1, l2, l3;
            split2(xr4.x, h0, l0); split2(xr4.y, h1, l1);
            split2(xr4.z, h2, l2); split2(xr4.w, h3, l3);
            uint2 hv, lv;
            hv.x = (unsigned)h0 | ((unsigned)h1 << 16); hv.y = (unsigned)h2 | ((unsigned)h3 << 16);
            lv.x = (unsigned)l0 | ((unsigned)l1 << 16); lv.y = (unsigned)l2 | ((unsigned)l3 << 16);
            *(uint2*)&phn[am * LDP + ak * 4] = hv;
            *(uint2*)&pln[am * LDP + ak * 4] = lv;
        } else {
            unsigned short h_, l_;
            split2(xr1, h_, l_);
            phn[am * LDP + ak] = h_;
            pln[am * LDP + ak] = l_;
        }
        // ---- prefetch x(t+2) (wrapped; last iters re-read valid steps) ----
        {
            const int tp = (t + 2) & (TT - 1);
            if (I == 64) xr4 = *(const float4*)&xin[((size_t)(base + am) * TT + tp) * 64 + ak * 4];
            else         xr1 = xin[((size_t)(base + am) * TT + tp) * 16 + ak];
        }
        __syncthreads();  // one barrier per step
    }
}

// ---------------- output MLP: 64 -> 32 relu -> 4 ----------------
__global__ __launch_bounds__(256)
void mlp_out_kernel(const float* __restrict__ hin,
                    const float* __restrict__ wo1, const float* __restrict__ bo1,
                    const float* __restrict__ wo2, const float* __restrict__ bo2,
                    float* __restrict__ out) {
    __shared__ __align__(16) float wo1_s[32 * 64];
    __shared__ float bo1_s[32];
    __shared__ float wo2_s[4 * 32];
    __shared__ float bo2_s[4];
    const int tid = threadIdx.x;
    for (int e = tid; e < 32 * 64; e += 256) wo1_s[e] = wo1[e];
    if (tid < 32) bo1_s[tid] = bo1[tid];
    if (tid < 128) wo2_s[tid] = wo2[tid];
    if (tid < 4) bo2_s[tid] = bo2[tid];
    __syncthreads();

    const int gid = blockIdx.x * 256 + tid;
    const float4* hv = (const float4*)(hin + gid * 64);
    float4 h[16];
#pragma unroll
    for (int q = 0; q < 16; ++q) h[q] = hv[q];

    float m1[32];
#pragma unroll
    for (int o = 0; o < 32; ++o) {
        float acc = bo1_s[o];
        const float4* wrow = (const float4*)(wo1_s + o * 64);
#pragma unroll
        for (int q = 0; q < 16; ++q) {
            const float4 w = wrow[q];
            acc = fmaf(h[q].x, w.x, acc);
            acc = fmaf(h[q].y, w.y, acc);
            acc = fmaf(h[q].z, w.z, acc);
            acc = fmaf(h[q].w, w.w, acc);
        }
        m1[o] = fmaxf(0.f, acc);
    }
    float r[4];
#pragma unroll
    for (int q = 0; q < 4; ++q) {
        float acc = bo2_s[q];
#pragma unroll
        for (int o = 0; o < 32; ++o) acc = fmaf(m1[o], wo2_s[q * 32 + o], acc);
        r[q] = acc;
    }
    float4 res;
    res.x = r[0]; res.y = r[1]; res.z = r[2]; res.w = r[3];
    ((float4*)out)[gid] = res;
}

extern "C" void kernel_launch(void* const* d_in, const int* in_sizes, int n_in,
                              void* d_out, int out_size, void* d_ws, size_t ws_size,
                              hipStream_t stream) {
    const float* x     = (const float*)d_in[0];
    const float* w1    = (const float*)d_in[1];
    const float* b1    = (const float*)d_in[2];
    const float* w2    = (const float*)d_in[3];
    const float* b2    = (const float*)d_in[4];
    const float* w_ih0 = (const float*)d_in[5];
    const float* w_hh0 = (const float*)d_in[6];
    const float* b_ih0 = (const float*)d_in[7];
    const float* b_hh0 = (const float*)d_in[8];
    const float* w_ih  = (const float*)d_in[9];
    const float* w_hh  = (const float*)d_in[10];
    const float* b_ih  = (const float*)d_in[11];
    const float* b_hh  = (const float*)d_in[12];
    const float* wo1   = (const float*)d_in[13];
    const float* bo1   = (const float*)d_in[14];
    const float* wo2   = (const float*)d_in[15];
    const float* bo2   = (const float*)d_in[16];

    // workspace: buf_mlp B*T*16 | bufA B*T*64 | bufB B*T*64  (fp32)
    float* buf_mlp = (float*)d_ws;
    float* bufA = buf_mlp + (size_t)BATCH * TT * 16;
    float* bufB = bufA + (size_t)BATCH * TT * 64;

    const int nbt_blocks = (BATCH * TT) / 256;  // 512

    mlp_in_kernel<<<nbt_blocks, 256, 0, stream>>>(x, w1, b1, w2, b2, buf_mlp);

    lstm_layer<16, 32><<<BATCH / 16, 256, 0, stream>>>(buf_mlp, w_ih0, w_hh0, b_ih0, b_hh0, bufA);

    const float* cur = bufA;
    float* nxt = bufB;
    for (int l = 0; l < 7; ++l) {
        lstm_layer<64, 64><<<BATCH / 16, 256, 0, stream>>>(
            cur, w_ih + (size_t)l * 256 * 64, w_hh + (size_t)l * 256 * 64,
            b_ih + (size_t)l * 256, b_hh + (size_t)l * 256, nxt);
        const float* tmp = nxt;
        nxt = (float*)cur;
        cur = tmp;
    }

    mlp_out_kernel<<<nbt_blocks, 256, 0, stream>>>(cur, wo1, bo1, wo2, bo2, (float*)d_out);
}

// Round 5
// 571.461 us; speedup vs baseline: 23.5446x; 1.1283x over previous
//
#include <hip/hip_runtime.h>

// x[2048,64,2] -> MLP(2->16 relu ->16) -> 8x LSTM(H=64) -> MLP(64->32 relu ->4)
// fp32 in/out. LSTM via split-bf16 MFMA (3-term, ~fp32 accuracy).
//
// Round 5: full-chip, overlap-friendly layer kernel.
//   grid 256 x 512 threads (8 waves = 2/SIMD on every CU), M=8 batch rows/block.
//   Wave w owns n-tiles {2w,2w+1} of the 256 gate rows: 24 MFMAs/wave/step, no k-split.
//   Gates -> LDS (GS=272: 2-way-free) -> phase C 1 slot/thread (c in 1 VGPR).
//   Panel (x|h, bf16 hi/lo) parity double-buffered, LDP=136 (2-way-free b128 reads).
//   2 barriers/step; x(t+1) register-prefetched.

#define BATCH 2048
#define TT 64
#define HH 64
#define LDP 136   // panel row stride in shorts
#define GS  272   // gate LDS row stride in floats

typedef short bf16x8 __attribute__((ext_vector_type(8)));
typedef float f32x4 __attribute__((ext_vector_type(4)));

__device__ __forceinline__ float sigmoid_fast(float x) {
    // exp handles +-inf gracefully: rcp(inf)=0, rcp(1)=1 -> no clamp needed
    return __builtin_amdgcn_rcpf(1.f + __expf(-x));
}
__device__ __forceinline__ float tanh_fast(float x) {
    float e = __expf(-2.f * x);
    e = fminf(e, 1e30f);          // keep 1+e finite so rcp>0: tanh(-big) -> -1, not NaN
    return (1.f - e) * __builtin_amdgcn_rcpf(1.f + e);
}
__device__ __forceinline__ void split2(float x, unsigned short& hi, unsigned short& lo) {
    const unsigned u = __float_as_uint(x);
    hi = (unsigned short)(u >> 16);
    const float r = x - __uint_as_float(u & 0xFFFF0000u);  // exact
    lo = (unsigned short)(__float_as_uint(r) >> 16);
}

// ---------------- input MLP: 2 -> 16 relu -> 16 ----------------
__global__ __launch_bounds__(256)
void mlp_in_kernel(const float* __restrict__ x,
                   const float* __restrict__ w1, const float* __restrict__ b1,
                   const float* __restrict__ w2, const float* __restrict__ b2,
                   float* __restrict__ out) {
    const int gid = blockIdx.x * 256 + threadIdx.x;
    const float x0 = x[gid * 2 + 0];
    const float x1 = x[gid * 2 + 1];
    float hid[16];
#pragma unroll
    for (int j = 0; j < 16; ++j) {
        float v = fmaf(x1, w1[j * 2 + 1], fmaf(x0, w1[j * 2 + 0], b1[j]));
        hid[j] = fmaxf(0.f, v);
    }
    float o[16];
#pragma unroll
    for (int oo = 0; oo < 16; ++oo) {
        float acc = b2[oo];
#pragma unroll
        for (int j = 0; j < 16; ++j) acc = fmaf(hid[j], w2[oo * 16 + j], acc);
        o[oo] = acc;
    }
    float4* op = (float4*)(out + gid * 16);
#pragma unroll
    for (int q = 0; q < 4; ++q) {
        float4 v;
        v.x = o[q * 4 + 0]; v.y = o[q * 4 + 1]; v.z = o[q * 4 + 2]; v.w = o[q * 4 + 3];
        op[q] = v;
    }
}

// ---------------- LSTM layer, split-bf16 MFMA, M=8, 512 threads ----------------
// I = real input width; IPAD = padded x-region; K = IPAD + 64.
template <int I, int IPAD>
__global__ __launch_bounds__(512, 2)
void lstm_layer(const float* __restrict__ xin,
                const float* __restrict__ w_ih, const float* __restrict__ w_hh,
                const float* __restrict__ b_ih, const float* __restrict__ b_hh,
                float* __restrict__ hout) {
    constexpr int K = IPAD + 64;
    constexpr int KT = K / 32;
    __shared__ unsigned short ph[2][16 * LDP];  // parity panels, hi plane (rows 8..15 stay 0)
    __shared__ unsigned short pl[2][16 * LDP];  // lo plane
    __shared__ float gs[8 * GS];                // gates [m][n]

    const int tid = threadIdx.x;
    const int wv = tid >> 6, lane = tid & 63, l16 = lane & 15, quad = lane >> 4;
    const int base = blockIdx.x * 8;

    for (int e = tid; e < 16 * LDP; e += 512) {
        ph[0][e] = 0; pl[0][e] = 0; ph[1][e] = 0; pl[1][e] = 0;
    }

    // --- weight B-fragments: wave wv owns n-tiles {2wv, 2wv+1} (cols of the 256 gate rows) ---
    // frag[kt][ntl]: lane(quad,l16) holds B[k=kt*32+quad*8+j][n=(2wv+ntl)*16+l16]
    bf16x8 bhi[KT][2], blo[KT][2];
    float bsum[2];
#pragma unroll
    for (int ntl = 0; ntl < 2; ++ntl) {
        const int n = (2 * wv + ntl) * 16 + l16;
        bsum[ntl] = b_ih[n] + b_hh[n];
#pragma unroll
        for (int kt = 0; kt < KT; ++kt) {
#pragma unroll
            for (int j = 0; j < 8; ++j) {
                const int k = kt * 32 + quad * 8 + j;
                float w = 0.f;
                if (k < I) w = w_ih[n * I + k];
                else if (k >= IPAD) w = w_hh[n * 64 + (k - IPAD)];
                unsigned short h_, l_;
                split2(w, h_, l_);
                bhi[kt][ntl][j] = (short)h_;
                blo[kt][ntl][j] = (short)l_;
            }
        }
    }

    // phase C slot: thread owns (m = tid>>6, j = tid&63); c in one VGPR
    float c = 0.f;
    const int cm = tid >> 6, cj = tid & 63;

    // staging: thread -> (row am, col ak)
    const int am = (I == 64) ? (tid >> 6) : (tid >> 4);
    const int ak = (I == 64) ? (tid & 63) : (tid & 15);
    const bool stg = (I == 64) ? true : (tid < 128);

    float xr = 0.f;
    if (stg) xr = xin[((size_t)(base + am) * TT + 0) * I + ak];
    if (stg) {
        unsigned short h_, l_;
        split2(xr, h_, l_);
        ph[0][am * LDP + ak] = h_;
        pl[0][am * LDP + ak] = l_;
    }
    if (stg) xr = xin[((size_t)(base + am) * TT + 1) * I + ak];
    __syncthreads();

    for (int t = 0; t < TT; ++t) {
        const int pb = t & 1;
        const unsigned short* php = ph[pb];
        const unsigned short* plp = pl[pb];
        unsigned short* phn = ph[pb ^ 1];
        unsigned short* pln = pl[pb ^ 1];

        // ---- phase B: gates = bias + [x|h] @ W^T (3-term split-bf16 MFMA) ----
        f32x4 acc[2];
#pragma unroll
        for (int ntl = 0; ntl < 2; ++ntl) {
            acc[ntl][0] = bsum[ntl]; acc[ntl][1] = bsum[ntl];
            acc[ntl][2] = bsum[ntl]; acc[ntl][3] = bsum[ntl];
        }
#pragma unroll
        for (int kt = 0; kt < KT; ++kt) {
            const int aoff = l16 * LDP + kt * 32 + quad * 8;
            const bf16x8 ahi = *(const bf16x8*)&php[aoff];
            const bf16x8 alo = *(const bf16x8*)&plp[aoff];
#pragma unroll
            for (int ntl = 0; ntl < 2; ++ntl) {
                acc[ntl] = __builtin_amdgcn_mfma_f32_16x16x32_bf16(ahi, bhi[kt][ntl], acc[ntl], 0, 0, 0);
                acc[ntl] = __builtin_amdgcn_mfma_f32_16x16x32_bf16(alo, bhi[kt][ntl], acc[ntl], 0, 0, 0);
                acc[ntl] = __builtin_amdgcn_mfma_f32_16x16x32_bf16(ahi, blo[kt][ntl], acc[ntl], 0, 0, 0);
            }
        }
        // D: row = quad*4+r (rows 0..7 real), col = l16. Write gates to LDS.
        if (quad < 2) {
#pragma unroll
            for (int ntl = 0; ntl < 2; ++ntl) {
                const int n = (2 * wv + ntl) * 16 + l16;
#pragma unroll
                for (int r = 0; r < 4; ++r) gs[(quad * 4 + r) * GS + n] = acc[ntl][r];
            }
        }
        __syncthreads();  // gs ready (also: everyone done reading panel[pb])

        // ---- phase C: one (m,j) slot per thread, register-local c ----
        {
            const float gi = gs[cm * GS + 0 + cj];
            const float gf = gs[cm * GS + 64 + cj];
            const float gg = gs[cm * GS + 128 + cj];
            const float go = gs[cm * GS + 192 + cj];
            const float iv = sigmoid_fast(gi), fv = sigmoid_fast(gf);
            const float gv = tanh_fast(gg), ov = sigmoid_fast(go);
            c = fv * c + iv * gv;
            const float h = ov * tanh_fast(c);
            unsigned short h_, l_;
            split2(h, h_, l_);
            phn[cm * LDP + IPAD + cj] = h_;
            pln[cm * LDP + IPAD + cj] = l_;
            hout[((size_t)(base + cm) * TT + t) * HH + cj] = h;
        }

        // ---- phase A: stage prefetched x(t+1) into next panel; prefetch x(t+2) ----
        if (stg) {
            unsigned short h_, l_;
            split2(xr, h_, l_);
            phn[am * LDP + ak] = h_;
            pln[am * LDP + ak] = l_;
            const int tp = (t + 2) & (TT - 1);
            xr = xin[((size_t)(base + am) * TT + tp) * I + ak];
        }
        __syncthreads();  // panel[pb^1] ready
    }
}

// ---------------- output MLP: 64 -> 32 relu -> 4 ----------------
__global__ __launch_bounds__(256)
void mlp_out_kernel(const float* __restrict__ hin,
                    const float* __restrict__ wo1, const float* __restrict__ bo1,
                    const float* __restrict__ wo2, const float* __restrict__ bo2,
                    float* __restrict__ out) {
    __shared__ __align__(16) float wo1_s[32 * 64];
    __shared__ float bo1_s[32];
    __shared__ float wo2_s[4 * 32];
    __shared__ float bo2_s[4];
    const int tid = threadIdx.x;
    for (int e = tid; e < 32 * 64; e += 256) wo1_s[e] = wo1[e];
    if (tid < 32) bo1_s[tid] = bo1[tid];
    if (tid < 128) wo2_s[tid] = wo2[tid];
    if (tid < 4) bo2_s[tid] = bo2[tid];
    __syncthreads();

    const int gid = blockIdx.x * 256 + tid;
    const float4* hv = (const float4*)(hin + gid * 64);
    float4 h[16];
#pragma unroll
    for (int q = 0; q < 16; ++q) h[q] = hv[q];

    float m1[32];
#pragma unroll
    for (int o = 0; o < 32; ++o) {
        float acc = bo1_s[o];
        const float4* wrow = (const float4*)(wo1_s + o * 64);
#pragma unroll
        for (int q = 0; q < 16; ++q) {
            const float4 w = wrow[q];
            acc = fmaf(h[q].x, w.x, acc);
            acc = fmaf(h[q].y, w.y, acc);
            acc = fmaf(h[q].z, w.z, acc);
            acc = fmaf(h[q].w, w.w, acc);
        }
        m1[o] = fmaxf(0.f, acc);
    }
    float r[4];
#pragma unroll
    for (int q = 0; q < 4; ++q) {
        float acc = bo2_s[q];
#pragma unroll
        for (int o = 0; o < 32; ++o) acc = fmaf(m1[o], wo2_s[q * 32 + o], acc);
        r[q] = acc;
    }
    float4 res;
    res.x = r[0]; res.y = r[1]; res.z = r[2]; res.w = r[3];
    ((float4*)out)[gid] = res;
}

extern "C" void kernel_launch(void* const* d_in, const int* in_sizes, int n_in,
                              void* d_out, int out_size, void* d_ws, size_t ws_size,
                              hipStream_t stream) {
    const float* x     = (const float*)d_in[0];
    const float* w1    = (const float*)d_in[1];
    const float* b1    = (const float*)d_in[2];
    const float* w2    = (const float*)d_in[3];
    const float* b2    = (const float*)d_in[4];
    const float* w_ih0 = (const float*)d_in[5];
    const float* w_hh0 = (const float*)d_in[6];
    const float* b_ih0 = (const float*)d_in[7];
    const float* b_hh0 = (const float*)d_in[8];
    const float* w_ih  = (const float*)d_in[9];
    const float* w_hh  = (const float*)d_in[10];
    const float* b_ih  = (const float*)d_in[11];
    const float* b_hh  = (const float*)d_in[12];
    const float* wo1   = (const float*)d_in[13];
    const float* bo1   = (const float*)d_in[14];
    const float* wo2   = (const float*)d_in[15];
    const float* bo2   = (const float*)d_in[16];

    // workspace: buf_mlp B*T*16 | bufA B*T*64 | bufB B*T*64  (fp32)
    float* buf_mlp = (float*)d_ws;
    float* bufA = buf_mlp + (size_t)BATCH * TT * 16;
    float* bufB = bufA + (size_t)BATCH * TT * 64;

    const int nbt_blocks = (BATCH * TT) / 256;  // 512

    mlp_in_kernel<<<nbt_blocks, 256, 0, stream>>>(x, w1, b1, w2, b2, buf_mlp);

    lstm_layer<16, 32><<<BATCH / 8, 512, 0, stream>>>(buf_mlp, w_ih0, w_hh0, b_ih0, b_hh0, bufA);

    const float* cur = bufA;
    float* nxt = bufB;
    for (int l = 0; l < 7; ++l) {
        lstm_layer<64, 64><<<BATCH / 8, 512, 0, stream>>>(
            cur, w_ih + (size_t)l * 256 * 64, w_hh + (size_t)l * 256 * 64,
            b_ih + (size_t)l * 256, b_hh + (size_t)l * 256, nxt);
        const float* tmp = nxt;
        nxt = (float*)cur;
        cur = tmp;
    }

    mlp_out_kernel<<<nbt_blocks, 256, 0, stream>>>(cur, wo1, bo1, wo2, bo2, (float*)d_out);
}